// Round 9
// baseline (293.931 us; speedup 1.0000x reference)
//
#include <hip/hip_runtime.h>
#include <math.h>

#define NN 100000
#define NE 1600000
#define D 64
#define NG 2000
#define LN_EPS 1e-5f
#define NB ((NN + 255) / 256)        // 391 buckets of 256 nodes
#define NBK NB
#define NTILE ((NN + 63) / 64)       // 1563
#define EPB 6400                     // edges per partition block (250 blocks)
#define NPART (NE / EPB)             // 250
#define CAP 6144                     // bucket capacity (expected 4096, ~32 sigma slack)
#define LSTR 72                      // padded LDS row stride (shorts), 144B = 9*16
#define WFRAG_MLP 24576              // 3 layers * 2 mats * 4096
#define WFRAG_TOT 26624              // + gate 2048
#define CONV4 (NN * D / 4)           // 1600000 float4-quads
#define CONV4BLK ((CONV4 + 1023) / 1024)  // 1563
#define WPREP1K (WFRAG_TOT / 1024)   // 26

typedef __attribute__((ext_vector_type(8))) short short8;            // 8 bf16 in 4 VGPRs
typedef __attribute__((ext_vector_type(8))) unsigned short ushort8;  // 16B row slice
typedef __attribute__((ext_vector_type(4))) float floatx4;           // MFMA accumulator

__device__ __forceinline__ unsigned short f2bf(float f) {
    unsigned int u = __float_as_uint(f);
    u += 0x7FFF + ((u >> 16) & 1);   // round-to-nearest-even
    return (unsigned short)(u >> 16);
}
__device__ __forceinline__ float bfu2f(unsigned short v) {
    return __uint_as_float(((unsigned int)v) << 16);
}

// ========== fused prep+partition: [part blocks | x->bf16 conv (x4) | weight frag] ==========
__global__ __launch_bounds__(1024) void k_prep_part(const float* __restrict__ x,
                                                    unsigned short* __restrict__ xb,
                                                    const float* __restrict__ W1,
                                                    const float* __restrict__ W2,
                                                    const float* __restrict__ gw1,
                                                    unsigned short* __restrict__ wfrag,
                                                    const int* __restrict__ src,
                                                    const int* __restrict__ dst,
                                                    int* __restrict__ bcur,
                                                    unsigned int* __restrict__ colbuf) {
    __shared__ int lcnt[NBK];
    __shared__ int lbase[NBK];
    int b = blockIdx.x;
    int tid = threadIdx.x;

    if (b < NPART) {
        int e0 = b * EPB;
        for (int i = tid; i < NBK; i += 1024) lcnt[i] = 0;
        __syncthreads();

        for (int e = tid; e < EPB; e += 1024)
            atomicAdd(&lcnt[dst[e0 + e] >> 8], 1);
        __syncthreads();

        for (int i = tid; i < NBK; i += 1024) {
            int c = lcnt[i];
            lbase[i] = c ? (i * CAP + atomicAdd(&bcur[i * 16], c)) : 0;
            lcnt[i] = 0;
        }
        __syncthreads();

        for (int e = tid; e < EPB; e += 1024) {
            int d = dst[e0 + e];
            int s = src[e0 + e];
            int bk = d >> 8;
            int pos = lbase[bk] + atomicAdd(&lcnt[bk], 1);
            colbuf[pos] = ((unsigned int)s << 8) | (unsigned int)(d & 255);
        }
    } else if (b < NPART + CONV4BLK) {
        int i4 = (b - NPART) * 1024 + tid;
        if (i4 < CONV4) {
            float4 v = ((const float4*)x)[i4];
            ushort4 o;
            o.x = f2bf(v.x); o.y = f2bf(v.y); o.z = f2bf(v.z); o.w = f2bf(v.w);
            ((ushort4*)xb)[i4] = o;
        }
    } else {
        int idx = (b - NPART - CONV4BLK) * 1024 + tid;
        if (idx < WFRAG_MLP) {
            int l = idx / 8192;
            int rem = idx % 8192;
            int mat = rem / 4096;
            int r2 = rem % 4096;
            int ks = r2 / 2048;
            int c = (r2 / 512) % 4;
            int lane = (r2 / 8) % 64;
            int j = r2 % 8;
            int n = lane & 15, q = lane >> 4;
            int k = ks * 32 + q * 8 + j;
            int col = c * 16 + n;
            const float* Wm = mat ? W2 : W1;
            wfrag[idx] = f2bf(Wm[l * 4096 + k * 64 + col]);
        } else if (idx < WFRAG_TOT) {
            int g = idx - WFRAG_MLP;
            int ks = g / 1024;
            int c = (g / 512) % 2;
            int lane = (g / 8) % 64;
            int j = g % 8;
            int n = lane & 15, q = lane >> 4;
            int k = ks * 32 + q * 8 + j;
            wfrag[idx] = f2bf(gw1[k * 32 + c * 16 + n]);
        }
    }
}

// phase C: per-bucket (LDS-staged) histogram + scan -> row_start/row_end, then scatter
// col into a SEPARATE col buffer. Segment read from global exactly once.
__global__ __launch_bounds__(256) void k_bfill(const unsigned int* __restrict__ colbuf,
                                               const int* __restrict__ bcur,
                                               int* __restrict__ rps,
                                               int* __restrict__ rpe,
                                               int* __restrict__ col) {
    __shared__ unsigned int sld[CAP];   // 24.6 KB segment stage (391 blocks -> LDS free)
    __shared__ int lcur[256];
    __shared__ int wsum[4];
    int b = blockIdx.x;
    int ebase = b * CAP;
    int cnt = bcur[b * 16];
    int nb0 = b * 256;
    int nodes = min(256, NN - nb0);
    int tid = threadIdx.x;
    int lane = tid & 63;
    int w = tid >> 6;

    for (int e = tid; e < cnt; e += 256) sld[e] = colbuf[ebase + e];
    lcur[tid] = 0;
    __syncthreads();

    for (int e = tid; e < cnt; e += 256)
        atomicAdd(&lcur[sld[e] & 255], 1);
    __syncthreads();

    int v = lcur[tid];
    int x = v;
#pragma unroll
    for (int off = 1; off < 64; off <<= 1) {
        int u = __shfl_up(x, off, 64);
        if (lane >= off) x += u;
    }
    if (lane == 63) wsum[w] = x;
    __syncthreads();
    int base = ebase;
    for (int k = 0; k < w; k++) base += wsum[k];
    int rp = base + x - v;
    if (tid < nodes) {
        rps[nb0 + tid] = rp;
        rpe[nb0 + tid] = rp + v;
    }
    lcur[tid] = rp;
    __syncthreads();

    for (int e = tid; e < cnt; e += 256) {
        unsigned int p = sld[e];
        int pos = atomicAdd(&lcur[p & 255], 1);
        col[pos] = p >> 8;
    }
}

// ========== fully wave-private fused layer: gather(16 nodes/wave) + MFMA + LN(+gate) ====
// Wave = 16 nodes for BOTH phases; zero barriers; setprio(1) around the MFMA clusters
// so MLP-phase waves preempt gather-stalled waves on the same SIMD (T5 regime:
// independent waves at different phases).
template <int LAST>
__global__ __launch_bounds__(256) void k_layer(const unsigned short* __restrict__ xin,
                                               unsigned short* __restrict__ xout,
                                               const int* __restrict__ rps,
                                               const int* __restrict__ rpe,
                                               const int* __restrict__ col,
                                               const float* __restrict__ epsp,
                                               const short8* __restrict__ wf,
                                               const short8* __restrict__ gf,
                                               const float* __restrict__ b1,
                                               const float* __restrict__ b2,
                                               const float* __restrict__ lng,
                                               const float* __restrict__ lnb,
                                               const float* __restrict__ gb1,
                                               const float* __restrict__ gw2,
                                               const float* __restrict__ gb2,
                                               float* __restrict__ gate) {
    __shared__ __align__(16) unsigned short smH[4][16 * LSTR];  // gathered rows
    __shared__ __align__(16) unsigned short smA[4][16 * LSTR];  // post-SiLU transpose
    int w = threadIdx.x >> 6;
    int lane = threadIdx.x & 63;
    int n = lane & 15;        // node within wave tile
    int fl = lane >> 4;       // feature quarter 0..3 (32B slice)
    int base = blockIdx.x * 64 + w * 16;
    int node = base + n;
    int nc = min(node, NN - 1);
    int st = rps[nc];
    int en = (node < NN) ? rpe[nc] : st;
    float ev = 1.0f + *epsp;

    // ---- gather phase (wave-private) ----
    float a[16];
#pragma unroll
    for (int e = 0; e < 16; e++) a[e] = 0.f;

    int nwin = (en - st + 3) >> 2;
#pragma unroll
    for (int off = 1; off < 64; off <<= 1) nwin = max(nwin, __shfl_xor(nwin, off, 64));

    const unsigned short* xrow = xin + ((size_t)nc << 6) + fl * 16;
    ushort8 xs0 = *(const ushort8*)(xrow);
    ushort8 xs1 = *(const ushort8*)(xrow + 8);

    for (int t = 0; t < nwin; t++) {
        int b0 = st + t * 4;
        int ce = b0 + fl;
        int c0 = (ce < en) ? col[ce] : -1;
        ushort8 v0[4], v1[4];
        unsigned int m = 0;
#pragma unroll
        for (int j = 0; j < 4; j++) {
            int idx = __shfl(c0, n + j * 16, 64);
            if (idx >= 0) {
                const ushort8* p = (const ushort8*)(xin + ((size_t)idx << 6) + fl * 16);
                v0[j] = p[0];
                v1[j] = p[1];
                m |= 1u << j;
            }
        }
#pragma unroll
        for (int j = 0; j < 4; j++)
            if (m & (1u << j)) {
#pragma unroll
                for (int e = 0; e < 8; e++) {
                    a[e] += bfu2f(v0[j][e]);
                    a[8 + e] += bfu2f(v1[j][e]);
                }
            }
    }

    {
        ushort8 o0, o1;
#pragma unroll
        for (int e = 0; e < 8; e++) {
            o0[e] = f2bf(ev * bfu2f(xs0[e]) + a[e]);
            o1[e] = f2bf(ev * bfu2f(xs1[e]) + a[8 + e]);
        }
        unsigned short* hw = smH[w] + n * LSTR + fl * 16;
        *(ushort8*)(hw) = o0;
        *(ushort8*)(hw + 8) = o1;
    }
    // no __syncthreads: wave reads only its own LDS region

    // ---- MFMA MLP + LN phase (same wave, q == fl) ----
    int q = fl;

    short8 B1f[2][4], B2f[2][4];
#pragma unroll
    for (int ks = 0; ks < 2; ks++)
#pragma unroll
        for (int c = 0; c < 4; c++) {
            B1f[ks][c] = wf[(ks * 4 + c) * 64 + lane];
            B2f[ks][c] = wf[512 + (ks * 4 + c) * 64 + lane];
        }
    short8 B3f[2][2];
    if (LAST) {
#pragma unroll
        for (int ks = 0; ks < 2; ks++)
#pragma unroll
            for (int c = 0; c < 2; c++)
                B3f[ks][c] = gf[(ks * 2 + c) * 64 + lane];
    }

    float b1v[4], b2v[4], lgv[4], lbv[4];
#pragma unroll
    for (int c = 0; c < 4; c++) {
        b1v[c] = b1[c * 16 + n];
        b2v[c] = b2[c * 16 + n];
        lgv[c] = lng[c * 16 + n];
        lbv[c] = lnb[c * 16 + n];
    }
    float gb1v[2], gw2v[2], gb2v = 0.f;
    if (LAST) {
        gb1v[0] = gb1[n]; gb1v[1] = gb1[16 + n];
        gw2v[0] = gw2[n]; gw2v[1] = gw2[16 + n];
        gb2v = gb2[0];
    }

    unsigned short* aw = smA[w];

    const short8* hp = (const short8*)(smH[w] + n * LSTR);
    short8 A0 = hp[q];
    short8 A1 = hp[4 + q];

    __builtin_amdgcn_s_setprio(1);
    floatx4 acc1[4];
#pragma unroll
    for (int c = 0; c < 4; c++) {
        floatx4 a1 = {b1v[c], b1v[c], b1v[c], b1v[c]};
        a1 = __builtin_amdgcn_mfma_f32_16x16x32_bf16(A0, B1f[0][c], a1, 0, 0, 0);
        a1 = __builtin_amdgcn_mfma_f32_16x16x32_bf16(A1, B1f[1][c], a1, 0, 0, 0);
        acc1[c] = a1;
    }
    __builtin_amdgcn_s_setprio(0);

#pragma unroll
    for (int c = 0; c < 4; c++)
#pragma unroll
        for (int r = 0; r < 4; r++) {
            float v = acc1[c][r];
            v = v / (1.0f + __expf(-v));
            aw[(q * 4 + r) * LSTR + c * 16 + n] = f2bf(v);
        }

    const short8* ap = (const short8*)(aw + n * LSTR);
    short8 A20 = ap[q];
    short8 A21 = ap[4 + q];

    __builtin_amdgcn_s_setprio(1);
    floatx4 acc2[4];
#pragma unroll
    for (int c = 0; c < 4; c++) {
        floatx4 a2 = {b2v[c], b2v[c], b2v[c], b2v[c]};
        a2 = __builtin_amdgcn_mfma_f32_16x16x32_bf16(A20, B2f[0][c], a2, 0, 0, 0);
        a2 = __builtin_amdgcn_mfma_f32_16x16x32_bf16(A21, B2f[1][c], a2, 0, 0, 0);
        acc2[c] = a2;
    }
    __builtin_amdgcn_s_setprio(0);

    float mu[4], inv[4];
#pragma unroll
    for (int r = 0; r < 4; r++) {
        float s = acc2[0][r] + acc2[1][r] + acc2[2][r] + acc2[3][r];
#pragma unroll
        for (int off = 1; off < 16; off <<= 1) s += __shfl_xor(s, off, 64);
        mu[r] = s * (1.0f / 64.0f);
        float d0 = acc2[0][r] - mu[r], d1 = acc2[1][r] - mu[r];
        float d2 = acc2[2][r] - mu[r], d3 = acc2[3][r] - mu[r];
        float vv = d0 * d0 + d1 * d1 + d2 * d2 + d3 * d3;
#pragma unroll
        for (int off = 1; off < 16; off <<= 1) vv += __shfl_xor(vv, off, 64);
        inv[r] = rsqrtf(vv * (1.0f / 64.0f) + LN_EPS);
    }

#pragma unroll
    for (int c = 0; c < 4; c++)
#pragma unroll
        for (int r = 0; r < 4; r++) {
            int onode = base + q * 4 + r;
            float o = (acc2[c][r] - mu[r]) * inv[r] * lgv[c] + lbv[c];
            unsigned short ob = f2bf(o);
            if (onode < NN) xout[((size_t)onode << 6) + c * 16 + n] = ob;
            if (LAST) aw[(q * 4 + r) * LSTR + c * 16 + n] = ob;
        }

    if (LAST) {
        short8 G0 = ap[q];
        short8 G1 = ap[4 + q];
        __builtin_amdgcn_s_setprio(1);
        floatx4 acc3[2];
#pragma unroll
        for (int c = 0; c < 2; c++) {
            floatx4 a3 = {gb1v[c], gb1v[c], gb1v[c], gb1v[c]};
            a3 = __builtin_amdgcn_mfma_f32_16x16x32_bf16(G0, B3f[0][c], a3, 0, 0, 0);
            a3 = __builtin_amdgcn_mfma_f32_16x16x32_bf16(G1, B3f[1][c], a3, 0, 0, 0);
            acc3[c] = a3;
        }
        __builtin_amdgcn_s_setprio(0);
#pragma unroll
        for (int r = 0; r < 4; r++) {
            float v0 = acc3[0][r];
            v0 = v0 / (1.0f + __expf(-v0));
            float v1 = acc3[1][r];
            v1 = v1 / (1.0f + __expf(-v1));
            float gsum = v0 * gw2v[0] + v1 * gw2v[1];
#pragma unroll
            for (int off = 1; off < 16; off <<= 1) gsum += __shfl_xor(gsum, off, 64);
            int onode = base + q * 4 + r;
            if (n == 0 && onode < NN) gate[onode] = gsum + gb2v;
        }
    }
}

// ================= per-graph softmax pooling =================
__global__ __launch_bounds__(256) void k_pool(const unsigned short* __restrict__ xf,
                                              const float* __restrict__ gate,
                                              const int* __restrict__ batch,
                                              float* __restrict__ out) {
    __shared__ float redm[4];
    __shared__ float reds[4];
    __shared__ float racc[4][D];
    int g = blockIdx.x;
    int w = threadIdx.x >> 6;
    int lane = threadIdx.x & 63;

    int lo = 0, hi = NN;
    while (lo < hi) { int mid = (lo + hi) >> 1; if (batch[mid] < g) lo = mid + 1; else hi = mid; }
    int start = lo;
    hi = NN;
    while (lo < hi) { int mid = (lo + hi) >> 1; if (batch[mid] < g + 1) lo = mid + 1; else hi = mid; }
    int end = lo;

    if (start >= end) {
        if (w == 0) out[((size_t)g << 6) + lane] = 0.0f;
        return;
    }

    float m = -INFINITY;
    for (int i = start + (int)threadIdx.x; i < end; i += 256) m = fmaxf(m, gate[i]);
#pragma unroll
    for (int mm = 32; mm >= 1; mm >>= 1) m = fmaxf(m, __shfl_xor(m, mm, 64));
    if (lane == 0) redm[w] = m;
    __syncthreads();
    m = fmaxf(fmaxf(redm[0], redm[1]), fmaxf(redm[2], redm[3]));

    float s = 0.0f;
    for (int i = start + (int)threadIdx.x; i < end; i += 256) s += __expf(gate[i] - m);
#pragma unroll
    for (int mm = 32; mm >= 1; mm >>= 1) s += __shfl_xor(s, mm, 64);
    if (lane == 0) reds[w] = s;
    __syncthreads();
    s = (reds[0] + reds[1]) + (reds[2] + reds[3]);

    float acc = 0.0f;
    for (int i = start + w; i < end; i += 4)
        acc += __expf(gate[i] - m) * bfu2f(xf[((size_t)i << 6) + lane]);
    racc[w][lane] = acc;
    __syncthreads();
    if (w == 0)
        out[((size_t)g << 6) + lane] =
            ((racc[0][lane] + racc[1][lane]) + (racc[2][lane] + racc[3][lane])) / s;
}

extern "C" void kernel_launch(void* const* d_in, const int* in_sizes, int n_in,
                              void* d_out, int out_size, void* d_ws, size_t ws_size,
                              hipStream_t stream) {
    const float* x   = (const float*)d_in[0];
    const int* ei    = (const int*)d_in[1];
    const int* batch = (const int*)d_in[2];
    const float* W1  = (const float*)d_in[3];
    const float* b1  = (const float*)d_in[4];
    const float* W2  = (const float*)d_in[5];
    const float* b2  = (const float*)d_in[6];
    const float* eps = (const float*)d_in[7];
    const float* lng = (const float*)d_in[8];
    const float* lnb = (const float*)d_in[9];
    const float* gw1 = (const float*)d_in[10];
    const float* gb1 = (const float*)d_in[11];
    const float* gw2 = (const float*)d_in[12];
    const float* gb2 = (const float*)d_in[13];

    const int* src = ei;
    const int* dst = ei + NE;

    // workspace layout (~46 MB)
    unsigned short* xb    = (unsigned short*)d_ws;              // NN*64 bf16 (ping)
    unsigned short* h     = xb + (size_t)NN * D;                // NN*64 bf16 (pong)
    float* gate           = (float*)(h + (size_t)NN * D);       // NN f32
    int* rps              = (int*)(gate + NN);                  // NN
    int* rpe              = rps + NN;                           // NN
    int* colbuf           = rpe + NN;                           // NBK*CAP (bucketed, tagged)
    int* col              = colbuf + (size_t)NBK * CAP;         // NBK*CAP (node-sorted)
    int* bcur             = col + (size_t)NBK * CAP;            // NBK*16 counts
    unsigned short* wfrag = (unsigned short*)(bcur + NBK * 16); // WFRAG_TOT

    float* out = (float*)d_out;

    // ---- CSR build + prep ----
    hipMemsetAsync(bcur, 0, NBK * 16 * sizeof(int), stream);
    k_prep_part<<<NPART + CONV4BLK + WPREP1K, 1024, 0, stream>>>(
        x, xb, W1, W2, gw1, wfrag, src, dst, bcur, (unsigned int*)colbuf);
    k_bfill<<<NBK, 256, 0, stream>>>((unsigned int*)colbuf, bcur, rps, rpe, col);

    const short8* wf0 = (const short8*)(wfrag);
    const short8* wf1 = (const short8*)(wfrag + 8192);
    const short8* wf2 = (const short8*)(wfrag + 16384);
    const short8* gf  = (const short8*)(wfrag + WFRAG_MLP);

    // ---- 3 fused GIN layers (wave-private: no barriers, no idle waves) ----
    k_layer<0><<<NTILE, 256, 0, stream>>>(xb, h, rps, rpe, col, eps + 0, wf0, gf,
        b1 + 0 * D, b2 + 0 * D, lng + 0 * D, lnb + 0 * D, gb1, gw2, gb2, gate);

    k_layer<0><<<NTILE, 256, 0, stream>>>(h, xb, rps, rpe, col, eps + 1, wf1, gf,
        b1 + 1 * D, b2 + 1 * D, lng + 1 * D, lnb + 1 * D, gb1, gw2, gb2, gate);

    k_layer<1><<<NTILE, 256, 0, stream>>>(xb, h, rps, rpe, col, eps + 2, wf2, gf,
        b1 + 2 * D, b2 + 2 * D, lng + 2 * D, lnb + 2 * D, gb1, gw2, gb2, gate);

    k_pool<<<NG, 256, 0, stream>>>(h, gate, batch, out);
}

// Round 10
// 278.335 us; speedup vs baseline: 1.0560x; 1.0560x over previous
//
#include <hip/hip_runtime.h>
#include <math.h>

#define NN 100000
#define NE 1600000
#define D 64
#define NG 2000
#define LN_EPS 1e-5f
#define NB ((NN + 255) / 256)        // 391 buckets of 256 nodes
#define NBK NB
#define NTILE ((NN + 63) / 64)       // 1563
#define EPB 6400                     // edges per partition block (250 blocks)
#define NPART (NE / EPB)             // 250
#define CAP 6144                     // bucket capacity (expected 4096, ~32 sigma slack)
#define LSTR 72                      // padded LDS row stride (shorts), 144B = 9*16
#define WFRAG_MLP 24576              // 3 layers * 2 mats * 4096
#define WFRAG_TOT 26624              // + gate 2048
#define CONV4 (NN * D / 4)           // 1600000 float4-quads
#define CONV4BLK ((CONV4 + 1023) / 1024)  // 1563
#define WPREP1K (WFRAG_TOT / 1024)   // 26

typedef __attribute__((ext_vector_type(8))) short short8;            // 8 bf16 in 4 VGPRs
typedef __attribute__((ext_vector_type(8))) unsigned short ushort8;  // 16B row slice
typedef __attribute__((ext_vector_type(4))) float floatx4;           // MFMA accumulator

__device__ __forceinline__ unsigned short f2bf(float f) {
    unsigned int u = __float_as_uint(f);
    u += 0x7FFF + ((u >> 16) & 1);   // round-to-nearest-even
    return (unsigned short)(u >> 16);
}
__device__ __forceinline__ float bfu2f(unsigned short v) {
    return __uint_as_float(((unsigned int)v) << 16);
}

// ========== fused prep+partition: [part blocks | x->bf16 conv (x4) | weight frag] ==========
__global__ __launch_bounds__(1024) void k_prep_part(const float* __restrict__ x,
                                                    unsigned short* __restrict__ xb,
                                                    const float* __restrict__ W1,
                                                    const float* __restrict__ W2,
                                                    const float* __restrict__ gw1,
                                                    unsigned short* __restrict__ wfrag,
                                                    const int* __restrict__ src,
                                                    const int* __restrict__ dst,
                                                    int* __restrict__ bcur,
                                                    unsigned int* __restrict__ colbuf) {
    __shared__ int lcnt[NBK];
    __shared__ int lbase[NBK];
    int b = blockIdx.x;
    int tid = threadIdx.x;

    if (b < NPART) {
        int e0 = b * EPB;
        for (int i = tid; i < NBK; i += 1024) lcnt[i] = 0;
        __syncthreads();

        for (int e = tid; e < EPB; e += 1024)
            atomicAdd(&lcnt[dst[e0 + e] >> 8], 1);
        __syncthreads();

        for (int i = tid; i < NBK; i += 1024) {
            int c = lcnt[i];
            lbase[i] = c ? (i * CAP + atomicAdd(&bcur[i * 16], c)) : 0;
            lcnt[i] = 0;
        }
        __syncthreads();

        for (int e = tid; e < EPB; e += 1024) {
            int d = dst[e0 + e];
            int s = src[e0 + e];
            int bk = d >> 8;
            int pos = lbase[bk] + atomicAdd(&lcnt[bk], 1);
            colbuf[pos] = ((unsigned int)s << 8) | (unsigned int)(d & 255);
        }
    } else if (b < NPART + CONV4BLK) {
        int i4 = (b - NPART) * 1024 + tid;
        if (i4 < CONV4) {
            float4 v = ((const float4*)x)[i4];
            ushort4 o;
            o.x = f2bf(v.x); o.y = f2bf(v.y); o.z = f2bf(v.z); o.w = f2bf(v.w);
            ((ushort4*)xb)[i4] = o;
        }
    } else {
        int idx = (b - NPART - CONV4BLK) * 1024 + tid;
        if (idx < WFRAG_MLP) {
            int l = idx / 8192;
            int rem = idx % 8192;
            int mat = rem / 4096;
            int r2 = rem % 4096;
            int ks = r2 / 2048;
            int c = (r2 / 512) % 4;
            int lane = (r2 / 8) % 64;
            int j = r2 % 8;
            int n = lane & 15, q = lane >> 4;
            int k = ks * 32 + q * 8 + j;
            int col = c * 16 + n;
            const float* Wm = mat ? W2 : W1;
            wfrag[idx] = f2bf(Wm[l * 4096 + k * 64 + col]);
        } else if (idx < WFRAG_TOT) {
            int g = idx - WFRAG_MLP;
            int ks = g / 1024;
            int c = (g / 512) % 2;
            int lane = (g / 8) % 64;
            int j = g % 8;
            int n = lane & 15, q = lane >> 4;
            int k = ks * 32 + q * 8 + j;
            wfrag[idx] = f2bf(gw1[k * 32 + c * 16 + n]);
        }
    }
}

// phase C: per-bucket (LDS-staged) histogram + scan -> row_start/row_end, then scatter
// col into a SEPARATE col buffer. Segment read from global exactly once.
__global__ __launch_bounds__(256) void k_bfill(const unsigned int* __restrict__ colbuf,
                                               const int* __restrict__ bcur,
                                               int* __restrict__ rps,
                                               int* __restrict__ rpe,
                                               int* __restrict__ col) {
    __shared__ unsigned int sld[CAP];   // 24.6 KB segment stage (391 blocks -> LDS free)
    __shared__ int lcur[256];
    __shared__ int wsum[4];
    int b = blockIdx.x;
    int ebase = b * CAP;
    int cnt = bcur[b * 16];
    int nb0 = b * 256;
    int nodes = min(256, NN - nb0);
    int tid = threadIdx.x;
    int lane = tid & 63;
    int w = tid >> 6;

    for (int e = tid; e < cnt; e += 256) sld[e] = colbuf[ebase + e];
    lcur[tid] = 0;
    __syncthreads();

    for (int e = tid; e < cnt; e += 256)
        atomicAdd(&lcur[sld[e] & 255], 1);
    __syncthreads();

    int v = lcur[tid];
    int x = v;
#pragma unroll
    for (int off = 1; off < 64; off <<= 1) {
        int u = __shfl_up(x, off, 64);
        if (lane >= off) x += u;
    }
    if (lane == 63) wsum[w] = x;
    __syncthreads();
    int base = ebase;
    for (int k = 0; k < w; k++) base += wsum[k];
    int rp = base + x - v;
    if (tid < nodes) {
        rps[nb0 + tid] = rp;
        rpe[nb0 + tid] = rp + v;
    }
    lcur[tid] = rp;
    __syncthreads();

    for (int e = tid; e < cnt; e += 256) {
        unsigned int p = sld[e];
        int pos = atomicAdd(&lcur[p & 255], 1);
        col[pos] = p >> 8;
    }
}

// ========== fully wave-private fused layer: gather(16 nodes/wave) + MFMA + LN(+gate) ====
// Wave = 16 nodes for BOTH phases: gather uses 4 lanes/node x 32B/lane (window of 4
// edges -> 8x16B loads in flight per lane), writes rows to the wave's private LDS
// region, then runs its own 16-node MFMA tile. ZERO barriers, zero idle waves,
// no global h traffic. NO setprio: R9 showed it bloats VGPR 56->80 and costs
// 2 waves/SIMD of occupancy on this latency-bound kernel.
template <int LAST>
__global__ __launch_bounds__(256) void k_layer(const unsigned short* __restrict__ xin,
                                               unsigned short* __restrict__ xout,
                                               const int* __restrict__ rps,
                                               const int* __restrict__ rpe,
                                               const int* __restrict__ col,
                                               const float* __restrict__ epsp,
                                               const short8* __restrict__ wf,
                                               const short8* __restrict__ gf,
                                               const float* __restrict__ b1,
                                               const float* __restrict__ b2,
                                               const float* __restrict__ lng,
                                               const float* __restrict__ lnb,
                                               const float* __restrict__ gb1,
                                               const float* __restrict__ gw2,
                                               const float* __restrict__ gb2,
                                               float* __restrict__ gate) {
    __shared__ __align__(16) unsigned short smH[4][16 * LSTR];  // gathered rows
    __shared__ __align__(16) unsigned short smA[4][16 * LSTR];  // post-SiLU transpose
    int w = threadIdx.x >> 6;
    int lane = threadIdx.x & 63;
    int n = lane & 15;        // node within wave tile
    int fl = lane >> 4;       // feature quarter 0..3 (32B slice)
    int base = blockIdx.x * 64 + w * 16;
    int node = base + n;
    int nc = min(node, NN - 1);
    int st = rps[nc];
    int en = (node < NN) ? rpe[nc] : st;
    float ev = 1.0f + *epsp;

    // ---- gather phase (wave-private) ----
    float a[16];
#pragma unroll
    for (int e = 0; e < 16; e++) a[e] = 0.f;

    // uniform window count across the wave (max over its 16 nodes)
    int nwin = (en - st + 3) >> 2;
#pragma unroll
    for (int off = 1; off < 64; off <<= 1) nwin = max(nwin, __shfl_xor(nwin, off, 64));

    const unsigned short* xrow = xin + ((size_t)nc << 6) + fl * 16;
    ushort8 xs0 = *(const ushort8*)(xrow);
    ushort8 xs1 = *(const ushort8*)(xrow + 8);

    for (int t = 0; t < nwin; t++) {
        int b0 = st + t * 4;
        int ce = b0 + fl;                       // this lane carries edge (t*4+fl) of node n
        int c0 = (ce < en) ? col[ce] : -1;
        ushort8 v0[4], v1[4];
        unsigned int m = 0;
#pragma unroll
        for (int j = 0; j < 4; j++) {
            int idx = __shfl(c0, n + j * 16, 64);
            if (idx >= 0) {
                const ushort8* p = (const ushort8*)(xin + ((size_t)idx << 6) + fl * 16);
                v0[j] = p[0];
                v1[j] = p[1];
                m |= 1u << j;
            }
        }
#pragma unroll
        for (int j = 0; j < 4; j++)
            if (m & (1u << j)) {
#pragma unroll
                for (int e = 0; e < 8; e++) {
                    a[e] += bfu2f(v0[j][e]);
                    a[8 + e] += bfu2f(v1[j][e]);
                }
            }
    }

    {
        ushort8 o0, o1;
#pragma unroll
        for (int e = 0; e < 8; e++) {
            o0[e] = f2bf(ev * bfu2f(xs0[e]) + a[e]);
            o1[e] = f2bf(ev * bfu2f(xs1[e]) + a[8 + e]);
        }
        unsigned short* hw = smH[w] + n * LSTR + fl * 16;
        *(ushort8*)(hw) = o0;
        *(ushort8*)(hw + 8) = o1;
    }
    // no __syncthreads: wave reads only its own LDS region (compiler inserts lgkmcnt)

    // ---- MFMA MLP + LN phase (same wave, q == fl) ----
    int q = fl;

    short8 B1f[2][4], B2f[2][4];
#pragma unroll
    for (int ks = 0; ks < 2; ks++)
#pragma unroll
        for (int c = 0; c < 4; c++) {
            B1f[ks][c] = wf[(ks * 4 + c) * 64 + lane];
            B2f[ks][c] = wf[512 + (ks * 4 + c) * 64 + lane];
        }
    short8 B3f[2][2];
    if (LAST) {
#pragma unroll
        for (int ks = 0; ks < 2; ks++)
#pragma unroll
            for (int c = 0; c < 2; c++)
                B3f[ks][c] = gf[(ks * 2 + c) * 64 + lane];
    }

    float b1v[4], b2v[4], lgv[4], lbv[4];
#pragma unroll
    for (int c = 0; c < 4; c++) {
        b1v[c] = b1[c * 16 + n];
        b2v[c] = b2[c * 16 + n];
        lgv[c] = lng[c * 16 + n];
        lbv[c] = lnb[c * 16 + n];
    }
    float gb1v[2], gw2v[2], gb2v = 0.f;
    if (LAST) {
        gb1v[0] = gb1[n]; gb1v[1] = gb1[16 + n];
        gw2v[0] = gw2[n]; gw2v[1] = gw2[16 + n];
        gb2v = gb2[0];
    }

    unsigned short* aw = smA[w];

    const short8* hp = (const short8*)(smH[w] + n * LSTR);
    short8 A0 = hp[q];
    short8 A1 = hp[4 + q];

    floatx4 acc1[4];
#pragma unroll
    for (int c = 0; c < 4; c++) {
        floatx4 a1 = {b1v[c], b1v[c], b1v[c], b1v[c]};
        a1 = __builtin_amdgcn_mfma_f32_16x16x32_bf16(A0, B1f[0][c], a1, 0, 0, 0);
        a1 = __builtin_amdgcn_mfma_f32_16x16x32_bf16(A1, B1f[1][c], a1, 0, 0, 0);
        acc1[c] = a1;
    }

#pragma unroll
    for (int c = 0; c < 4; c++)
#pragma unroll
        for (int r = 0; r < 4; r++) {
            float v = acc1[c][r];
            v = v / (1.0f + __expf(-v));
            aw[(q * 4 + r) * LSTR + c * 16 + n] = f2bf(v);
        }

    const short8* ap = (const short8*)(aw + n * LSTR);
    short8 A20 = ap[q];
    short8 A21 = ap[4 + q];

    floatx4 acc2[4];
#pragma unroll
    for (int c = 0; c < 4; c++) {
        floatx4 a2 = {b2v[c], b2v[c], b2v[c], b2v[c]};
        a2 = __builtin_amdgcn_mfma_f32_16x16x32_bf16(A20, B2f[0][c], a2, 0, 0, 0);
        a2 = __builtin_amdgcn_mfma_f32_16x16x32_bf16(A21, B2f[1][c], a2, 0, 0, 0);
        acc2[c] = a2;
    }

    float mu[4], inv[4];
#pragma unroll
    for (int r = 0; r < 4; r++) {
        float s = acc2[0][r] + acc2[1][r] + acc2[2][r] + acc2[3][r];
#pragma unroll
        for (int off = 1; off < 16; off <<= 1) s += __shfl_xor(s, off, 64);
        mu[r] = s * (1.0f / 64.0f);
        float d0 = acc2[0][r] - mu[r], d1 = acc2[1][r] - mu[r];
        float d2 = acc2[2][r] - mu[r], d3 = acc2[3][r] - mu[r];
        float vv = d0 * d0 + d1 * d1 + d2 * d2 + d3 * d3;
#pragma unroll
        for (int off = 1; off < 16; off <<= 1) vv += __shfl_xor(vv, off, 64);
        inv[r] = rsqrtf(vv * (1.0f / 64.0f) + LN_EPS);
    }

#pragma unroll
    for (int c = 0; c < 4; c++)
#pragma unroll
        for (int r = 0; r < 4; r++) {
            int onode = base + q * 4 + r;
            float o = (acc2[c][r] - mu[r]) * inv[r] * lgv[c] + lbv[c];
            unsigned short ob = f2bf(o);
            if (onode < NN) xout[((size_t)onode << 6) + c * 16 + n] = ob;
            if (LAST) aw[(q * 4 + r) * LSTR + c * 16 + n] = ob;
        }

    if (LAST) {
        short8 G0 = ap[q];
        short8 G1 = ap[4 + q];
        floatx4 acc3[2];
#pragma unroll
        for (int c = 0; c < 2; c++) {
            floatx4 a3 = {gb1v[c], gb1v[c], gb1v[c], gb1v[c]};
            a3 = __builtin_amdgcn_mfma_f32_16x16x32_bf16(G0, B3f[0][c], a3, 0, 0, 0);
            a3 = __builtin_amdgcn_mfma_f32_16x16x32_bf16(G1, B3f[1][c], a3, 0, 0, 0);
            acc3[c] = a3;
        }
#pragma unroll
        for (int r = 0; r < 4; r++) {
            float v0 = acc3[0][r];
            v0 = v0 / (1.0f + __expf(-v0));
            float v1 = acc3[1][r];
            v1 = v1 / (1.0f + __expf(-v1));
            float gsum = v0 * gw2v[0] + v1 * gw2v[1];
#pragma unroll
            for (int off = 1; off < 16; off <<= 1) gsum += __shfl_xor(gsum, off, 64);
            int onode = base + q * 4 + r;
            if (n == 0 && onode < NN) gate[onode] = gsum + gb2v;
        }
    }
}

// ================= per-graph softmax pooling =================
__global__ __launch_bounds__(256) void k_pool(const unsigned short* __restrict__ xf,
                                              const float* __restrict__ gate,
                                              const int* __restrict__ batch,
                                              float* __restrict__ out) {
    __shared__ float redm[4];
    __shared__ float reds[4];
    __shared__ float racc[4][D];
    int g = blockIdx.x;
    int w = threadIdx.x >> 6;
    int lane = threadIdx.x & 63;

    int lo = 0, hi = NN;
    while (lo < hi) { int mid = (lo + hi) >> 1; if (batch[mid] < g) lo = mid + 1; else hi = mid; }
    int start = lo;
    hi = NN;
    while (lo < hi) { int mid = (lo + hi) >> 1; if (batch[mid] < g + 1) lo = mid + 1; else hi = mid; }
    int end = lo;

    if (start >= end) {
        if (w == 0) out[((size_t)g << 6) + lane] = 0.0f;
        return;
    }

    float m = -INFINITY;
    for (int i = start + (int)threadIdx.x; i < end; i += 256) m = fmaxf(m, gate[i]);
#pragma unroll
    for (int mm = 32; mm >= 1; mm >>= 1) m = fmaxf(m, __shfl_xor(m, mm, 64));
    if (lane == 0) redm[w] = m;
    __syncthreads();
    m = fmaxf(fmaxf(redm[0], redm[1]), fmaxf(redm[2], redm[3]));

    float s = 0.0f;
    for (int i = start + (int)threadIdx.x; i < end; i += 256) s += __expf(gate[i] - m);
#pragma unroll
    for (int mm = 32; mm >= 1; mm >>= 1) s += __shfl_xor(s, mm, 64);
    if (lane == 0) reds[w] = s;
    __syncthreads();
    s = (reds[0] + reds[1]) + (reds[2] + reds[3]);

    float acc = 0.0f;
    for (int i = start + w; i < end; i += 4)
        acc += __expf(gate[i] - m) * bfu2f(xf[((size_t)i << 6) + lane]);
    racc[w][lane] = acc;
    __syncthreads();
    if (w == 0)
        out[((size_t)g << 6) + lane] =
            ((racc[0][lane] + racc[1][lane]) + (racc[2][lane] + racc[3][lane])) / s;
}

extern "C" void kernel_launch(void* const* d_in, const int* in_sizes, int n_in,
                              void* d_out, int out_size, void* d_ws, size_t ws_size,
                              hipStream_t stream) {
    const float* x   = (const float*)d_in[0];
    const int* ei    = (const int*)d_in[1];
    const int* batch = (const int*)d_in[2];
    const float* W1  = (const float*)d_in[3];
    const float* b1  = (const float*)d_in[4];
    const float* W2  = (const float*)d_in[5];
    const float* b2  = (const float*)d_in[6];
    const float* eps = (const float*)d_in[7];
    const float* lng = (const float*)d_in[8];
    const float* lnb = (const float*)d_in[9];
    const float* gw1 = (const float*)d_in[10];
    const float* gb1 = (const float*)d_in[11];
    const float* gw2 = (const float*)d_in[12];
    const float* gb2 = (const float*)d_in[13];

    const int* src = ei;
    const int* dst = ei + NE;

    // workspace layout (~46 MB)
    unsigned short* xb    = (unsigned short*)d_ws;              // NN*64 bf16 (ping)
    unsigned short* h     = xb + (size_t)NN * D;                // NN*64 bf16 (pong)
    float* gate           = (float*)(h + (size_t)NN * D);       // NN f32
    int* rps              = (int*)(gate + NN);                  // NN
    int* rpe              = rps + NN;                           // NN
    int* colbuf           = rpe + NN;                           // NBK*CAP (bucketed, tagged)
    int* col              = colbuf + (size_t)NBK * CAP;         // NBK*CAP (node-sorted)
    int* bcur             = col + (size_t)NBK * CAP;            // NBK*16 counts
    unsigned short* wfrag = (unsigned short*)(bcur + NBK * 16); // WFRAG_TOT

    float* out = (float*)d_out;

    // ---- CSR build + prep ----
    hipMemsetAsync(bcur, 0, NBK * 16 * sizeof(int), stream);
    k_prep_part<<<NPART + CONV4BLK + WPREP1K, 1024, 0, stream>>>(
        x, xb, W1, W2, gw1, wfrag, src, dst, bcur, (unsigned int*)colbuf);
    k_bfill<<<NBK, 256, 0, stream>>>((unsigned int*)colbuf, bcur, rps, rpe, col);

    const short8* wf0 = (const short8*)(wfrag);
    const short8* wf1 = (const short8*)(wfrag + 8192);
    const short8* wf2 = (const short8*)(wfrag + 16384);
    const short8* gf  = (const short8*)(wfrag + WFRAG_MLP);

    // ---- 3 fused GIN layers (wave-private: no barriers, no idle waves) ----
    k_layer<0><<<NTILE, 256, 0, stream>>>(xb, h, rps, rpe, col, eps + 0, wf0, gf,
        b1 + 0 * D, b2 + 0 * D, lng + 0 * D, lnb + 0 * D, gb1, gw2, gb2, gate);

    k_layer<0><<<NTILE, 256, 0, stream>>>(h, xb, rps, rpe, col, eps + 1, wf1, gf,
        b1 + 1 * D, b2 + 1 * D, lng + 1 * D, lnb + 1 * D, gb1, gw2, gb2, gate);

    k_layer<1><<<NTILE, 256, 0, stream>>>(xb, h, rps, rpe, col, eps + 2, wf2, gf,
        b1 + 2 * D, b2 + 2 * D, lng + 2 * D, lnb + 2 * D, gb1, gw2, gb2, gate);

    k_pool<<<NG, 256, 0, stream>>>(h, gate, batch, out);
}